// Round 1
// baseline (254.910 us; speedup 1.0000x reference)
//
#include <hip/hip_runtime.h>

#define C_ 64
#define CI_ 32
#define N_ 4096
#define LOG2E 1.4426950408889634f
#define NBLK 256

typedef __attribute__((ext_vector_type(8))) short bf16x8;
typedef __attribute__((ext_vector_type(4))) float f32x4;

__device__ __forceinline__ unsigned short f2bf_rne(float f) {
  unsigned u = __builtin_bit_cast(unsigned, f);
  unsigned r = (u + 0x7FFFu + ((u >> 16) & 1u)) >> 16;
  return (unsigned short)r;
}
__device__ __forceinline__ unsigned pack_bf2(float lo, float hi) {
  unsigned a = (__builtin_bit_cast(unsigned, lo) + 0x8000u) >> 16;
  unsigned b = (__builtin_bit_cast(unsigned, hi) + 0x8000u) & 0xFFFF0000u;
  return a | b;
}
// async DMA global->LDS, 16B/lane; lds dst = wave-uniform base (+lane*16 by HW)
__device__ __forceinline__ void dma16(const void* gp, const void* lp) {
  __builtin_amdgcn_global_load_lds(
      (const __attribute__((address_space(1))) unsigned*)(unsigned long long)gp,
      (__attribute__((address_space(3))) unsigned*)(unsigned)(unsigned long long)lp,
      16, 0, 0);
}

// Device-scope grid barrier. Safe: 96KB LDS -> max 1 block/CU, grid=256=#CUs,
// so all blocks co-resident. bar[] zeroed by the memset node each iteration.
// __threadfence (agent scope) does L2 writeback/invalidate on CDNA, making
// pre-barrier plain stores visible to post-barrier plain loads across XCDs.
__device__ __forceinline__ void grid_sync(unsigned* bar) {
  __syncthreads();
  if (threadIdx.x == 0) {
    __threadfence();
    __hip_atomic_fetch_add(bar, 1u, __ATOMIC_RELAXED, __HIP_MEMORY_SCOPE_AGENT);
    unsigned spins = 0;
    while (__hip_atomic_load(bar, __ATOMIC_RELAXED, __HIP_MEMORY_SCOPE_AGENT) < NBLK) {
      __builtin_amdgcn_s_sleep(16);
      if (++spins > 1000000u) break;  // safety valve; never hit when resident
    }
    __threadfence();
  }
  __syncthreads();
}

// sigma (per 32-chunk): slot p=8q+j -> local idx 4q + (j&3) + 16*(j>>2).
//   phi2[b][ch][q][r=m_local][j]   g2[b][ch][q][i][j]   den[b][ch][p] (fp32)
//   ww2[c][p] = bf16( ww[c][sigma(p)] )
//
// Fused kernel: grid 256 x 1024 threads.
//  P1: projections. block=(b, n-tile of 64); thread-group g=tid>>8:
//      g0 theta(supp), g1 phi(ref), g2 gproj(ref), g3 aux(ww2 on bid16).
//  P2: den. block=(b, nq, mt4); 16 waves cover 256 m; theta quarter staged
//      4KB/phase double-buffered, shared by all 16 waves (was 4 -> 4x less DMA).
//  P3: attention + output. Same as previous K3, but P = exp2(f - log2 den)
//      via MFMA C-in = -log2(den)  (removes 16 v_mul per cc-iter + rcp pass).
__global__ __launch_bounds__(1024) void fused(
    const float* __restrict__ supp, const float* __restrict__ ref,
    const float* __restrict__ tw, const float* __restrict__ tb,
    const float* __restrict__ pw, const float* __restrict__ pb,
    const float* __restrict__ gw, const float* __restrict__ gb,
    const float* __restrict__ ww, const float* __restrict__ wb,
    unsigned short* __restrict__ theta, unsigned short* __restrict__ phi2,
    unsigned short* __restrict__ g2, float* __restrict__ den,
    unsigned short* __restrict__ ww2, unsigned* __restrict__ bar,
    float* __restrict__ out)
{
  __shared__ __align__(16) unsigned char LB[98304];  // 96KB: forces 1 block/CU
  const int tid = threadIdx.x;
  const int bid = blockIdx.x;
  const int lane = tid & 63;
  const int w = tid >> 6;
  const int row16 = lane & 15;
  const int quad = lane >> 4;

  // ================= P1: projections =================
  {
    const int b = bid >> 6;
    const int n0 = (bid & 63) << 6;
    const int g = tid >> 8;
    const int o = __builtin_amdgcn_readfirstlane(w & 3);
    const int n = n0 + lane;
    float (*gL)[66] = (float (*)[66])LB;

    if (g < 3) {
      const float *W, *bias, *src;
      if (g == 0)      { W = tw; bias = tb; src = supp; }
      else if (g == 1) { W = pw; bias = pb; src = ref; }
      else             { W = gw; bias = gb; src = ref; }
      const float* x = src + (size_t)b * (C_ * N_) + n;
      const float* Wo = W + o * 8 * C_;
      float acc[8];
#pragma unroll
      for (int k = 0; k < 8; k++) acc[k] = bias[o * 8 + k];
#pragma unroll 8
      for (int c = 0; c < C_; c++) {
        float v = x[(size_t)c * N_];
#pragma unroll
        for (int k = 0; k < 8; k++) acc[k] = fmaf(Wo[k * C_ + c], v, acc[k]);
      }
      if (g == 0) {
        unsigned pk[4];
#pragma unroll
        for (int k = 0; k < 4; k++)
          pk[k] = (unsigned)f2bf_rne(acc[2 * k] * LOG2E) |
                  ((unsigned)f2bf_rne(acc[2 * k + 1] * LOG2E) << 16);
        *(uint4*)(theta + (((size_t)b * N_ + n) << 5) + o * 8) = *(uint4*)pk;
      } else if (g == 1) {
        unsigned pk[4];
#pragma unroll
        for (int k = 0; k < 4; k++)
          pk[k] = (unsigned)f2bf_rne(acc[2 * k]) |
                  ((unsigned)f2bf_rne(acc[2 * k + 1]) << 16);
        size_t off = (((size_t)b * 128 + (n >> 5)) << 10) + o * 256 + (n & 31) * 8;
        *(uint4*)(phi2 + off) = *(uint4*)pk;
      } else {
#pragma unroll
        for (int k = 0; k < 8; k++) gL[o * 8 + k][lane] = acc[k];
      }
    } else {
      if (bid == 16) {
        for (int e = tid & 255; e < C_ * CI_; e += 256) {
          int p = e & 31;
          int i = 4 * ((p >> 3) & 3) + (p & 3) + 16 * ((p >> 2) & 1);
          ww2[e] = f2bf_rne(ww[(e >> 5) * CI_ + i]);
        }
      }
    }
    __syncthreads();
    if (g == 2) {
      const int t = tid & 255;
      const int c = t >> 7;
      const int rr2 = t & 127;
      const int q = rr2 >> 5;
      const int i = rr2 & 31;
      const float* g0 = &gL[i][c * 32 + 4 * q];
      unsigned pk[4];
      pk[0] = pack_bf2(g0[0], g0[1]);
      pk[1] = pack_bf2(g0[2], g0[3]);
      pk[2] = pack_bf2(g0[16], g0[17]);
      pk[3] = pack_bf2(g0[18], g0[19]);
      size_t off = (((size_t)b * 128 + (n0 >> 5) + c) << 10) + rr2 * 8;
      *(uint4*)(g2 + off) = *(uint4*)pk;
    }
  }

  grid_sync(&bar[0]);

  // ================= P2: denominators =================
  {
    const int b = bid >> 6;
    const int nq = (bid >> 4) & 3;
    const int mt4 = bid & 15;
    unsigned short (*TH)[2048] = (unsigned short (*)[2048])LB;  // 2 x 4KB

    // persistent B-frag: wave's 16 m = mt4*256 + w*16 + row16
    const int m256 = w * 16 + row16;
    bf16x8 bf = *(const bf16x8*)(phi2 +
        (((size_t)b * 128 + mt4 * 8 + (m256 >> 5)) << 10) + (quad << 8) +
        (m256 & 31) * 8);

    const unsigned short* thbase = theta + (((size_t)b * N_ + nq * 1024) << 5);
    if (w < 4) dma16(thbase + w * 512 + lane * 8, &TH[0][w * 512]);
    __syncthreads();

    f32x4 zero = {0.f, 0.f, 0.f, 0.f};
    float ds4[4] = {0.f, 0.f, 0.f, 0.f};
    for (int ph = 0; ph < 16; ph++) {
      const int buf = ph & 1;
      if (ph + 1 < 16 && w < 4)
        dma16(thbase + (ph + 1) * 2048 + w * 512 + lane * 8, &TH[buf ^ 1][w * 512]);
#pragma unroll
      for (int s = 0; s < 4; s++) {
        bf16x8 af = *(const bf16x8*)(&TH[buf][s * 512 + row16 * 32 + quad * 8]);
        f32x4 ff = __builtin_amdgcn_mfma_f32_16x16x32_bf16(af, bf, zero, 0, 0, 0);
#pragma unroll
        for (int r = 0; r < 4; r++) ds4[r] += __builtin_amdgcn_exp2f(ff[r]);
      }
      __syncthreads();
    }
    float v = (ds4[0] + ds4[1]) + (ds4[2] + ds4[3]);
    v += __shfl_xor(v, 16);
    v += __shfl_xor(v, 32);
    if (lane < 16) {
      int ml = w * 16 + lane;
      int ch = mt4 * 8 + (ml >> 5);
      int local = ml & 31;
      int q = (local & 15) >> 2;
      int j = (local & 3) | (((local >> 4) & 1) << 2);
      atomicAdd(&den[(((size_t)b * 128 + ch) << 5) + 8 * q + j], v);
    }
  }

  grid_sync(&bar[1]);

  // ================= P3: attention + output =================
  {
    const int b = bid >> 6;
    const int n0 = (bid & 63) << 6;
    const int ns = w & 3;
    const int q = w >> 2;
    unsigned short (*SB)[4][4096] = (unsigned short (*)[4][4096])LB;  // 64KB
    float* ldL = (float*)(LB + 65536);                                // 16KB

    for (int e = tid; e < 4096; e += 1024)
      ldL[e] = -__log2f(den[((size_t)b << 12) + e]);

    bf16x8 tB = *(const bf16x8*)(theta +
        (((size_t)b * N_ + n0 + ns * 16 + row16) << 5) + (quad << 3));

    const size_t chb = (size_t)b * 128;
    const int sq = w >> 2;

    f32x4 zero = {0.f, 0.f, 0.f, 0.f};
    f32x4 xa = zero, xb = zero;

#pragma unroll
    for (int s = 0; s < 2; s++) {
      int idx = w * 2 + s;
      int cc = (idx >> 2) & 1;
      int part = idx & 3;  // 0:phi-lo 1:phi-hi 2:g-lo 3:g-hi
      const unsigned short* src = (part >= 2 ? g2 : phi2) +
          ((chb + sq * 32 + cc) << 10) + ((size_t)(part & 1) << 9) + lane * 8;
      dma16(src, &SB[0][sq][cc * 2048 + (part >= 2 ? 1024 : 0) + ((part & 1) << 9)]);
    }
    __syncthreads();

    for (int ph = 0; ph < 16; ph++) {
      const int buf = ph & 1;
      if (ph + 1 < 16) {
#pragma unroll
        for (int s = 0; s < 2; s++) {
          int idx = w * 2 + s;
          int cc = (idx >> 2) & 1;
          int part = idx & 3;
          const unsigned short* src = (part >= 2 ? g2 : phi2) +
              ((chb + sq * 32 + (ph + 1) * 2 + cc) << 10) + ((size_t)(part & 1) << 9) + lane * 8;
          dma16(src, &SB[buf ^ 1][sq][cc * 2048 + (part >= 2 ? 1024 : 0) + ((part & 1) << 9)]);
        }
      }
#pragma unroll
      for (int cc = 0; cc < 2; cc++) {
        const unsigned short* base = &SB[buf][q][cc * 2048];
        bf16x8 pA0 = *(const bf16x8*)(base + (quad << 8) + row16 * 8);
        bf16x8 pA1 = *(const bf16x8*)(base + (quad << 8) + (row16 + 16) * 8);
        bf16x8 gA0 = *(const bf16x8*)(base + 1024 + (quad << 8) + row16 * 8);
        bf16x8 gA1 = *(const bf16x8*)(base + 1024 + (quad << 8) + (row16 + 16) * 8);
        const float* lp = &ldL[((q * 32 + ph * 2 + cc) << 5) + (quad << 3)];
        f32x4 l0 = *(const f32x4*)lp;
        f32x4 l1 = *(const f32x4*)(lp + 4);

        // C-in = -log2(den) at the exact element positions the old r-mult used
        f32x4 f0 = __builtin_amdgcn_mfma_f32_16x16x32_bf16(pA0, tB, l0, 0, 0, 0);
        f32x4 f1 = __builtin_amdgcn_mfma_f32_16x16x32_bf16(pA1, tB, l1, 0, 0, 0);

        uint4 d;
        d.x = pack_bf2(__builtin_amdgcn_exp2f(f0[0]), __builtin_amdgcn_exp2f(f0[1]));
        d.y = pack_bf2(__builtin_amdgcn_exp2f(f0[2]), __builtin_amdgcn_exp2f(f0[3]));
        d.z = pack_bf2(__builtin_amdgcn_exp2f(f1[0]), __builtin_amdgcn_exp2f(f1[1]));
        d.w = pack_bf2(__builtin_amdgcn_exp2f(f1[2]), __builtin_amdgcn_exp2f(f1[3]));
        bf16x8 Pb = __builtin_bit_cast(bf16x8, d);

        xa = __builtin_amdgcn_mfma_f32_16x16x32_bf16(gA0, Pb, xa, 0, 0, 0);
        xb = __builtin_amdgcn_mfma_f32_16x16x32_bf16(gA1, Pb, xb, 0, 0, 0);
      }
      __syncthreads();
    }

    // cross-quarter combine: quarters 1..3 spill to LDS (aliases SB), q0 sums
    float* part = (float*)LB;
    if (q) {
      float* dst = part + ((((q - 1) * 4 + ns) * 64 + lane) << 3);
#pragma unroll
      for (int r = 0; r < 4; r++) { dst[r] = xa[r]; dst[4 + r] = xb[r]; }
    }
    __syncthreads();
    if (q == 0) {
#pragma unroll
      for (int e = 0; e < 3; e++) {
        const float* s = part + (((e * 4 + ns) * 64 + lane) << 3);
#pragma unroll
        for (int r = 0; r < 4; r++) { xa[r] += s[r]; xb[r] += s[4 + r]; }
      }
      uint4 d;
      d.x = pack_bf2(xa[0], xa[1]);
      d.y = pack_bf2(xa[2], xa[3]);
      d.z = pack_bf2(xb[0], xb[1]);
      d.w = pack_bf2(xb[2], xb[3]);
      bf16x8 Bx = __builtin_bit_cast(bf16x8, d);
      const int nloc = n0 + ns * 16 + row16;
#pragma unroll
      for (int ct = 0; ct < 4; ct++) {
        bf16x8 aw = *(const bf16x8*)(ww2 + (ct * 16 + row16) * CI_ + (quad << 3));
        f32x4 o = __builtin_amdgcn_mfma_f32_16x16x32_bf16(aw, Bx, zero, 0, 0, 0);
#pragma unroll
        for (int r = 0; r < 4; r++) {
          int c = ct * 16 + quad * 4 + r;
          size_t ob = ((size_t)b * C_ + c) * N_ + nloc;
          out[ob] = o[r] + wb[c] + supp[ob];
        }
      }
    }
  }
}

extern "C" void kernel_launch(void* const* d_in, const int* in_sizes, int n_in,
                              void* d_out, int out_size, void* d_ws, size_t ws_size,
                              hipStream_t stream)
{
  const float* supp = (const float*)d_in[0];
  const float* ref  = (const float*)d_in[1];
  const float* tw   = (const float*)d_in[2];
  const float* tb   = (const float*)d_in[3];
  const float* pw   = (const float*)d_in[4];
  const float* pb   = (const float*)d_in[5];
  const float* gw   = (const float*)d_in[6];
  const float* gb   = (const float*)d_in[7];
  const float* ww   = (const float*)d_in[8];
  const float* wb   = (const float*)d_in[9];
  float* out = (float*)d_out;

  char* ws = (char*)d_ws;
  unsigned short* theta = (unsigned short*)ws;                        // 1 MB
  unsigned short* phi2  = (unsigned short*)(ws + (1u << 20));         // 1 MB
  unsigned short* g2    = (unsigned short*)(ws + (2u << 20));         // 1 MB
  float*          den   = (float*)(ws + (3u << 20));                  // 64 KB
  unsigned short* ww2   = (unsigned short*)(ws + (3u << 20) + 65536); // 4 KB
  unsigned*       bar   = (unsigned*)(ws + (3u << 20) + 65536 + 4096);

  // zero den + ww2 + barrier counters (re-zeroed every graph iteration)
  hipMemsetAsync(ws + (3u << 20), 0, 65536 + 4096 + 256, stream);
  hipLaunchKernelGGL(fused, dim3(NBLK), dim3(1024), 0, stream,
                     supp, ref, tw, tb, pw, pb, gw, gb, ww, wb,
                     theta, phi2, g2, den, ww2, bar, out);
}

// Round 2
// 112.554 us; speedup vs baseline: 2.2648x; 2.2648x over previous
//
#include <hip/hip_runtime.h>

#define C_ 64
#define CI_ 32
#define N_ 4096
#define LOG2E 1.4426950408889634f

typedef __attribute__((ext_vector_type(8))) short bf16x8;
typedef __attribute__((ext_vector_type(4))) float f32x4;

__device__ __forceinline__ unsigned short f2bf_rne(float f) {
  unsigned u = __builtin_bit_cast(unsigned, f);
  unsigned r = (u + 0x7FFFu + ((u >> 16) & 1u)) >> 16;
  return (unsigned short)r;
}
__device__ __forceinline__ unsigned pack_bf2(float lo, float hi) {
  unsigned a = (__builtin_bit_cast(unsigned, lo) + 0x8000u) >> 16;
  unsigned b = (__builtin_bit_cast(unsigned, hi) + 0x8000u) & 0xFFFF0000u;
  return a | b;
}
// async DMA global->LDS, 16B/lane; lds dst = wave-uniform base (+lane*16 by HW)
__device__ __forceinline__ void dma16(const void* gp, const void* lp) {
  __builtin_amdgcn_global_load_lds(
      (const __attribute__((address_space(1))) unsigned*)(unsigned long long)gp,
      (__attribute__((address_space(3))) unsigned*)(unsigned)(unsigned long long)lp,
      16, 0, 0);
}

// sigma (per 32-chunk): slot p=8q+j -> local idx 4q + (j&3) + 16*(j>>2).
//   phi2[b][ch][q][r=m_local][j]           (2KB/chunk, DMA-contiguous)
//   g2  [b][ch][q][i][j]  = g[i][ch*32+sigma(8q+j)]
//   den [b][ch][p]        (fp32, atomically accumulated)
//   ww2 [c][p]            = bf16( ww[c][sigma(p)] )

// ---------------------------------------------------------------------------
// K1: projections. Grid 768 = (proj x b x 64 n-tiles of 64). 256 thr; wave =
// channel octet o, lane = one position. theta pre-scaled by log2(e).
// Blocks 0..15 additionally zero den (replaces the memset graph node).
// ---------------------------------------------------------------------------
__global__ __launch_bounds__(256) void k1_proj(
    const float* __restrict__ supp, const float* __restrict__ ref,
    const float* __restrict__ tw, const float* __restrict__ tb,
    const float* __restrict__ pw, const float* __restrict__ pb,
    const float* __restrict__ gw, const float* __restrict__ gb,
    unsigned short* __restrict__ theta, unsigned short* __restrict__ phi2,
    unsigned short* __restrict__ g2, float* __restrict__ den)
{
  const int proj = blockIdx.x >> 8;
  const int rr = blockIdx.x & 255;
  const int b = rr >> 6;
  const int n0 = (rr & 63) << 6;
  const int o = __builtin_amdgcn_readfirstlane(threadIdx.x >> 6);
  const int lane = threadIdx.x & 63;
  const int n = n0 + lane;

  if (blockIdx.x < 16) {
    // zero den: 16 blocks x 256 thr x 4 floats = 16384
    uint4 z = {0u, 0u, 0u, 0u};
    *(uint4*)(den + blockIdx.x * 1024 + threadIdx.x * 4) = z;
  }

  __shared__ float gL[CI_][66];

  const float *W, *bias, *src;
  if (proj == 0)      { W = tw; bias = tb; src = supp; }
  else if (proj == 1) { W = pw; bias = pb; src = ref; }
  else                { W = gw; bias = gb; src = ref; }

  const float* x = src + (size_t)b * (C_ * N_) + n;
  const float* Wo = W + o * 8 * C_;
  float acc[8];
#pragma unroll
  for (int k = 0; k < 8; k++) acc[k] = bias[o * 8 + k];
#pragma unroll 8
  for (int c = 0; c < C_; c++) {
    float v = x[(size_t)c * N_];
#pragma unroll
    for (int k = 0; k < 8; k++) acc[k] = fmaf(Wo[k * C_ + c], v, acc[k]);
  }

  if (proj == 0) {
    unsigned pk[4];
#pragma unroll
    for (int k = 0; k < 4; k++)
      pk[k] = (unsigned)f2bf_rne(acc[2 * k] * LOG2E) |
              ((unsigned)f2bf_rne(acc[2 * k + 1] * LOG2E) << 16);
    *(uint4*)(theta + (((size_t)b * N_ + n) << 5) + o * 8) = *(uint4*)pk;
  } else if (proj == 1) {
    unsigned pk[4];
#pragma unroll
    for (int k = 0; k < 4; k++)
      pk[k] = (unsigned)f2bf_rne(acc[2 * k]) |
              ((unsigned)f2bf_rne(acc[2 * k + 1]) << 16);
    size_t off = (((size_t)b * 128 + (n >> 5)) << 10) + o * 256 + (n & 31) * 8;
    *(uint4*)(phi2 + off) = *(uint4*)pk;
  } else {
#pragma unroll
    for (int k = 0; k < 8; k++) gL[o * 8 + k][lane] = acc[k];
    __syncthreads();
    const int t = threadIdx.x;
    const int c = t >> 7;
    const int rr2 = t & 127;
    const int q = rr2 >> 5;
    const int i = rr2 & 31;
    const float* g0 = &gL[i][c * 32 + 4 * q];
    unsigned pk[4];
    pk[0] = pack_bf2(g0[0], g0[1]);
    pk[1] = pack_bf2(g0[2], g0[3]);
    pk[2] = pack_bf2(g0[16], g0[17]);
    pk[3] = pack_bf2(g0[18], g0[19]);
    size_t off = (((size_t)b * 128 + (n0 >> 5) + c) << 10) + rr2 * 8;
    *(uint4*)(g2 + off) = *(uint4*)pk;
  }
}

// ---------------------------------------------------------------------------
// K2: den[m] += sum over this block's n-quarter of exp2(f'). Grid 1024 =
// (b x 4 n-quarters x 64 m-tiles); 256 thr = 4 waves; wave = 16-m slice,
// persistent phi B-frag; theta DMA double-buffered (4KB/phase), 16 phases.
// Partials -> global atomicAdd. Block 0 also emits ww2.
// ---------------------------------------------------------------------------
__global__ __launch_bounds__(256) void k2_den(
    const unsigned short* __restrict__ theta, const unsigned short* __restrict__ phi2,
    const float* __restrict__ ww, float* __restrict__ den,
    unsigned short* __restrict__ ww2)
{
  const int mt = blockIdx.x & 63;
  const int nq = (blockIdx.x >> 6) & 3;
  const int b = blockIdx.x >> 8;
  const int tid = threadIdx.x;
  const int w = tid >> 6;
  const int lane = tid & 63;
  const int row16 = lane & 15;
  const int quad = lane >> 4;

  if (blockIdx.x == 0) {
    for (int e = tid; e < C_ * CI_; e += 256) {
      int p = e & 31;
      int i = 4 * ((p >> 3) & 3) + (p & 3) + 16 * ((p >> 2) & 1);
      ww2[e] = f2bf_rne(ww[(e >> 5) * CI_ + i]);
    }
  }

  __shared__ __align__(16) unsigned short TH[2][2048];   // 2 x 4KB

  // persistent B-frag: wave's m-16 = mt*64 + w*16 + row16
  bf16x8 bf = *(const bf16x8*)(phi2 +
      (((size_t)b * 128 + mt * 2 + (w >> 1)) << 10) + (quad << 8) +
      ((w & 1) * 16 + row16) * 8);

  const unsigned short* thbase = theta + (((size_t)b * N_ + nq * 1024) << 5);

  // prologue: stage phase 0 (wave w -> its 1KB segment)
  dma16(thbase + w * 512 + lane * 8, &TH[0][w * 512]);
  __syncthreads();

  f32x4 zero = {0.f, 0.f, 0.f, 0.f};
  float ds4[4] = {0.f, 0.f, 0.f, 0.f};

  for (int ph = 0; ph < 16; ph++) {
    const int buf = ph & 1;
    if (ph + 1 < 16)
      dma16(thbase + (ph + 1) * 2048 + w * 512 + lane * 8, &TH[buf ^ 1][w * 512]);
#pragma unroll
    for (int s = 0; s < 4; s++) {
      bf16x8 af = *(const bf16x8*)(&TH[buf][s * 512 + row16 * 32 + quad * 8]);
      f32x4 ff = __builtin_amdgcn_mfma_f32_16x16x32_bf16(af, bf, zero, 0, 0, 0);
#pragma unroll
      for (int r = 0; r < 4; r++) ds4[r] += __builtin_amdgcn_exp2f(ff[r]);
    }
    __syncthreads();
  }

  float v = (ds4[0] + ds4[1]) + (ds4[2] + ds4[3]);
  v += __shfl_xor(v, 16);
  v += __shfl_xor(v, 32);
  if (lane < 16) {
    int ml64 = w * 16 + lane;
    int ch = mt * 2 + (ml64 >> 5);
    int local = ml64 & 31;
    int q = (local & 15) >> 2;
    int j = (local & 3) | (((local >> 4) & 1) << 2);
    atomicAdd(&den[(((size_t)b * 128 + ch) << 5) + 8 * q + j], v);
  }
}

// ---------------------------------------------------------------------------
// K3: full attention + output projection + residual. Grid 256, 1024 thr =
// 16 waves (ns x m-quarter q). XCD-aware bijective swizzle: physical block p
// maps to batch b=(p&7)>>1, tile t=((p>>3)<<1)|(p&1), so each batch's 1MB
// phi2+g2 working set lives on exactly 2 XCDs (p%8 = XCD id) -> L2-resident,
// HBM refetch ~127MB -> ~8MB. P = exp2(f - log2 den) via MFMA C-in
// (removes rcp pass + 16 v_mul per cc-iter). LDS 80KB.
// ---------------------------------------------------------------------------
__global__ __launch_bounds__(1024) void k3_attn(
    const unsigned short* __restrict__ theta, const unsigned short* __restrict__ phi2,
    const unsigned short* __restrict__ g2, const float* __restrict__ den,
    const unsigned short* __restrict__ ww2, const float* __restrict__ wb,
    const float* __restrict__ supp, float* __restrict__ out)
{
  const int tid = threadIdx.x;
  const int w = tid >> 6;
  const int lane = tid & 63;
  const int p = blockIdx.x;
  const int b = (p & 7) >> 1;                       // XCD swizzle
  const int t = ((p >> 3) << 1) | (p & 1);
  const int n0 = t << 6;
  const int ns = w & 3;
  const int q = w >> 2;
  const int row16 = lane & 15;
  const int quad = lane >> 4;

  __shared__ __align__(16) unsigned short SB[2][4][4096];  // 64 KB
  __shared__ float ldL[4096];                              // 16 KB

  for (int e = tid; e < 4096; e += 1024)
    ldL[e] = -__log2f(den[((size_t)b << 12) + e]);

  bf16x8 tB = *(const bf16x8*)(theta +
      (((size_t)b * N_ + n0 + ns * 16 + row16) << 5) + (quad << 3));

  const size_t chb = (size_t)b * 128;
  const int sq = w >> 2;

  f32x4 zero = {0.f, 0.f, 0.f, 0.f};
  f32x4 xa = zero, xb = zero;

  // prologue: stage phase 0 into buf 0
#pragma unroll
  for (int s = 0; s < 2; s++) {
    int idx = w * 2 + s;
    int cc = (idx >> 2) & 1;
    int part = idx & 3;                  // 0:phi-lo 1:phi-hi 2:g-lo 3:g-hi
    const unsigned short* src = (part >= 2 ? g2 : phi2) +
        ((chb + sq * 32 + cc) << 10) + ((size_t)(part & 1) << 9) + lane * 8;
    dma16(src, &SB[0][sq][cc * 2048 + (part >= 2 ? 1024 : 0) + ((part & 1) << 9)]);
  }
  __syncthreads();

  for (int ph = 0; ph < 16; ph++) {
    const int buf = ph & 1;
    if (ph + 1 < 16) {
#pragma unroll
      for (int s = 0; s < 2; s++) {
        int idx = w * 2 + s;
        int cc = (idx >> 2) & 1;
        int part = idx & 3;
        const unsigned short* src = (part >= 2 ? g2 : phi2) +
            ((chb + sq * 32 + (ph + 1) * 2 + cc) << 10) + ((size_t)(part & 1) << 9) + lane * 8;
        dma16(src, &SB[buf ^ 1][sq][cc * 2048 + (part >= 2 ? 1024 : 0) + ((part & 1) << 9)]);
      }
    }
#pragma unroll
    for (int cc = 0; cc < 2; cc++) {
      const unsigned short* base = &SB[buf][q][cc * 2048];
      bf16x8 pA0 = *(const bf16x8*)(base + (quad << 8) + row16 * 8);
      bf16x8 pA1 = *(const bf16x8*)(base + (quad << 8) + (row16 + 16) * 8);
      bf16x8 gA0 = *(const bf16x8*)(base + 1024 + (quad << 8) + row16 * 8);
      bf16x8 gA1 = *(const bf16x8*)(base + 1024 + (quad << 8) + (row16 + 16) * 8);
      const float* lp = &ldL[((q * 32 + ph * 2 + cc) << 5) + (quad << 3)];
      f32x4 l0 = *(const f32x4*)lp;
      f32x4 l1 = *(const f32x4*)(lp + 4);

      // C-in = -log2(den) at the exact element positions the old r-mult used
      f32x4 f0 = __builtin_amdgcn_mfma_f32_16x16x32_bf16(pA0, tB, l0, 0, 0, 0);
      f32x4 f1 = __builtin_amdgcn_mfma_f32_16x16x32_bf16(pA1, tB, l1, 0, 0, 0);

      uint4 d;
      d.x = pack_bf2(__builtin_amdgcn_exp2f(f0[0]), __builtin_amdgcn_exp2f(f0[1]));
      d.y = pack_bf2(__builtin_amdgcn_exp2f(f0[2]), __builtin_amdgcn_exp2f(f0[3]));
      d.z = pack_bf2(__builtin_amdgcn_exp2f(f1[0]), __builtin_amdgcn_exp2f(f1[1]));
      d.w = pack_bf2(__builtin_amdgcn_exp2f(f1[2]), __builtin_amdgcn_exp2f(f1[3]));
      bf16x8 Pb = __builtin_bit_cast(bf16x8, d);

      xa = __builtin_amdgcn_mfma_f32_16x16x32_bf16(gA0, Pb, xa, 0, 0, 0);
      xb = __builtin_amdgcn_mfma_f32_16x16x32_bf16(gA1, Pb, xb, 0, 0, 0);
    }
    __syncthreads();
  }

  // cross-quarter combine: quarters 1..3 spill to LDS (aliases SB), q0 sums
  float* part = (float*)SB;
  if (q) {
    float* dst = part + ((((q - 1) * 4 + ns) * 64 + lane) << 3);
#pragma unroll
    for (int r = 0; r < 4; r++) { dst[r] = xa[r]; dst[4 + r] = xb[r]; }
  }
  __syncthreads();
  if (q == 0) {
#pragma unroll
    for (int e = 0; e < 3; e++) {
      const float* s = part + (((e * 4 + ns) * 64 + lane) << 3);
#pragma unroll
      for (int r = 0; r < 4; r++) { xa[r] += s[r]; xb[r] += s[4 + r]; }
    }
    uint4 d;
    d.x = pack_bf2(xa[0], xa[1]);
    d.y = pack_bf2(xa[2], xa[3]);
    d.z = pack_bf2(xb[0], xb[1]);
    d.w = pack_bf2(xb[2], xb[3]);
    bf16x8 Bx = __builtin_bit_cast(bf16x8, d);
    const int nloc = n0 + ns * 16 + row16;
#pragma unroll
    for (int ct = 0; ct < 4; ct++) {
      bf16x8 aw = *(const bf16x8*)(ww2 + (ct * 16 + row16) * CI_ + (quad << 3));
      f32x4 o = __builtin_amdgcn_mfma_f32_16x16x32_bf16(aw, Bx, zero, 0, 0, 0);
#pragma unroll
      for (int r = 0; r < 4; r++) {
        int c = ct * 16 + quad * 4 + r;
        size_t ob = ((size_t)b * C_ + c) * N_ + nloc;
        out[ob] = o[r] + wb[c] + supp[ob];
      }
    }
  }
}

extern "C" void kernel_launch(void* const* d_in, const int* in_sizes, int n_in,
                              void* d_out, int out_size, void* d_ws, size_t ws_size,
                              hipStream_t stream)
{
  const float* supp = (const float*)d_in[0];
  const float* ref  = (const float*)d_in[1];
  const float* tw   = (const float*)d_in[2];
  const float* tb   = (const float*)d_in[3];
  const float* pw   = (const float*)d_in[4];
  const float* pb   = (const float*)d_in[5];
  const float* gw   = (const float*)d_in[6];
  const float* gb   = (const float*)d_in[7];
  const float* ww   = (const float*)d_in[8];
  const float* wb   = (const float*)d_in[9];
  float* out = (float*)d_out;

  char* ws = (char*)d_ws;
  unsigned short* theta = (unsigned short*)ws;                       // 1 MB
  unsigned short* phi2  = (unsigned short*)(ws + (1u << 20));        // 1 MB
  unsigned short* g2    = (unsigned short*)(ws + (2u << 20));        // 1 MB
  float*          den   = (float*)(ws + (3u << 20));                 // 64 KB
  unsigned short* ww2   = (unsigned short*)(ws + (3u << 20) + 65536);// 4 KB

  hipLaunchKernelGGL(k1_proj, dim3(768), dim3(256), 0, stream,
                     supp, ref, tw, tb, pw, pb, gw, gb, theta, phi2, g2, den);
  hipLaunchKernelGGL(k2_den, dim3(1024), dim3(256), 0, stream,
                     theta, phi2, ww, den, ww2);
  hipLaunchKernelGGL(k3_attn, dim3(256), dim3(1024), 0, stream,
                     theta, phi2, g2, den, ww2, wb, supp, out);
}